// Round 1
// baseline (1432.376 us; speedup 1.0000x reference)
//
#include <hip/hip_runtime.h>

// Fused LayerNorm-LSTM cell + zoneout for MI355X (gfx950).
// GEMM: concat(x,h)[65536x512] @ W[512x1024] via mfma_f32_16x16x32_f16,
// fused with block-LN(4x256), gates, LN(new_c), zoneout.
// Kernel 0 pre-transposes W to Wt[1024][512] fp16 in d_ws (needs 1 MB ws).

#define NTHREADS 512
#define TILE_M 64
#define PRE_STRIDE 20  // halfs per n-row in epilogue scratch (16 rows + 4 pad)

typedef _Float16 half8 __attribute__((ext_vector_type(8)));
typedef _Float16 half4v __attribute__((ext_vector_type(4)));
typedef float float4v __attribute__((ext_vector_type(4)));

__device__ __forceinline__ void async16(const void* g, void* l) {
  __builtin_amdgcn_global_load_lds(
      (const __attribute__((address_space(1))) unsigned int*)g,
      (__attribute__((address_space(3))) unsigned int*)l, 16, 0, 0);
}

__device__ __forceinline__ float sigm(float x) {
  return __fdividef(1.0f, 1.0f + __expf(-x));
}
__device__ __forceinline__ float tanh_fast(float x) {
  return 2.0f * __fdividef(1.0f, 1.0f + __expf(-2.0f * x)) - 1.0f;
}

// ---- Kernel 0: W[512][1024] fp32 -> Wt[1024][512] fp16 (tiled transpose) ----
__global__ __launch_bounds__(256) void wt_kernel(const float* __restrict__ W,
                                                 _Float16* __restrict__ Wt) {
  __shared__ float tile[64][65];
  const int bn = blockIdx.x << 6;  // n block (16)
  const int bk = blockIdx.y << 6;  // k block (8)
  const int tid = threadIdx.x;
#pragma unroll
  for (int i = 0; i < 16; ++i) {
    int idx = (i << 8) + tid;
    int kk = idx >> 6, nn = idx & 63;
    tile[kk][nn] = W[(size_t)(bk + kk) * 1024 + bn + nn];
  }
  __syncthreads();
#pragma unroll
  for (int i = 0; i < 16; ++i) {
    int idx = (i << 8) + tid;
    int nn = idx >> 6, kk = idx & 63;
    Wt[(size_t)(bn + nn) * 512 + bk + kk] = (_Float16)tile[kk][nn];
  }
}

// ---- Main fused kernel ----
// Block: 64 rows x all 1024 cols. K-loop BK=32, W staged in two 512-col halves.
// LDS phase A: aT 64x32 halfs (4KB, 16B-chunk XOR swizzle) + wTh 512x32 halfs (32KB).
// LDS phase B: preT[1024][PRE_STRIDE] halfs (40KB), col-major (n-major, row inner).
__global__ __launch_bounds__(NTHREADS, 2) void lstm_fused(
    const float* __restrict__ x, const float* __restrict__ hin,
    const float* __restrict__ cin, const _Float16* __restrict__ Wt,
    const float* __restrict__ bias, const float* __restrict__ g1,
    const float* __restrict__ b1, const float* __restrict__ g2,
    const float* __restrict__ b2, const float* __restrict__ mhp,
    const float* __restrict__ mcp, float* __restrict__ out) {
  extern __shared__ char smem[];
  _Float16* aT = (_Float16*)smem;            // 4KB
  _Float16* wTh = (_Float16*)(smem + 4096);  // 32KB
  _Float16* preT = (_Float16*)smem;          // 40KB (phase B, reuses phase A)

  const int tid = threadIdx.x;
  const int wave = tid >> 6;
  const int lane = tid & 63;
  const int l15 = lane & 15;
  const int quad = lane >> 4;
  const int blockRow = blockIdx.x * TILE_M;

  float4v acc[4][8];
#pragma unroll
  for (int s = 0; s < 4; ++s)
#pragma unroll
    for (int c = 0; c < 8; ++c) acc[s][c] = (float4v){0.f, 0.f, 0.f, 0.f};

  // A staging: thread -> (row=tid>>3, 4 k's at (tid&7)*4), fp32->fp16, swizzled chunk
  const int arow = tid >> 3;
  const int ap4 = (tid & 7) << 2;
  const float* xrow = x + (size_t)(blockRow + arow) * 256 + ap4;
  const float* hrow = hin + (size_t)(blockRow + arow) * 256 + ap4;
  _Float16* adst = aT + arow * 32 + (((ap4 >> 3) ^ (arow & 3)) << 3) + (ap4 & 4);

  // W staging: lane-linear LDS (global_load_lds constraint); global chunk XOR-permuted
  const int wnl0 = tid >> 2;                  // local n row 0..127 (+ it*128)
  const int wj = (tid & 3) ^ (wnl0 & 3);      // global 16B chunk to fetch
  const char* wg = (const char*)Wt + (size_t)wnl0 * 1024 + wj * 16;
  char* wl = (char*)wTh + tid * 16;

  const int aslot = quad ^ (l15 & 3);  // swizzled chunk slot for all frag reads

  for (int iter = 0; iter < 16; ++iter) {
    {  // stage A tile (k window iter*32..+31 of concat(x,h))
      const float* src = (iter < 8) ? (xrow + iter * 32) : (hrow + (iter - 8) * 32);
      float4 v = *(const float4*)src;
      half4v hv = {(_Float16)v.x, (_Float16)v.y, (_Float16)v.z, (_Float16)v.w};
      *(half4v*)adst = hv;
    }
#pragma unroll
    for (int it = 0; it < 4; ++it)  // stage W cols 0..511
      async16(wg + it * 131072 + iter * 64, wl + it * 8192);
    __syncthreads();

    half8 af[4];
#pragma unroll
    for (int s = 0; s < 4; ++s)
      af[s] = *(const half8*)(aT + (s * 16 + l15) * 32 + aslot * 8);
    {
      half8 bf[4];
#pragma unroll
      for (int cc = 0; cc < 4; ++cc) {
        int nl = wave * 64 + cc * 16 + l15;
        bf[cc] = *(const half8*)(wTh + nl * 32 + aslot * 8);
      }
#pragma unroll
      for (int s = 0; s < 4; ++s)
#pragma unroll
        for (int cc = 0; cc < 4; ++cc)
          acc[s][cc] = __builtin_amdgcn_mfma_f32_16x16x32_f16(af[s], bf[cc], acc[s][cc], 0, 0, 0);
    }
    __syncthreads();
#pragma unroll
    for (int it = 0; it < 4; ++it)  // stage W cols 512..1023
      async16(wg + 524288 + it * 131072 + iter * 64, wl + it * 8192);
    __syncthreads();
    {
      half8 bf[4];
#pragma unroll
      for (int cc = 0; cc < 4; ++cc) {
        int nl = wave * 64 + cc * 16 + l15;
        bf[cc] = *(const half8*)(wTh + nl * 32 + aslot * 8);
      }
#pragma unroll
      for (int s = 0; s < 4; ++s)
#pragma unroll
        for (int cc = 0; cc < 4; ++cc)
          acc[s][4 + cc] =
              __builtin_amdgcn_mfma_f32_16x16x32_f16(af[s], bf[cc], acc[s][4 + cc], 0, 0, 0);
    }
    __syncthreads();
  }

  // ---- Epilogue: 4 passes of 16 rows (pass p == row-stripe p) ----
  float* out_h = out;
  float* out_c = out + (size_t)65536 * 256;
  const int er = tid >> 5;  // row in pass 0..15
  const int et = tid & 31;  // col phase: cols {et, et+32, ..., et+224}

#pragma unroll 1
  for (int p = 0; p < 4; ++p) {
    __syncthreads();
    // write acc stripe p -> preT (col-major: [n][row]), b64 per 4 rows
#pragma unroll
    for (int c = 0; c < 8; ++c) {
      int n = ((c >> 2) << 9) + wave * 64 + ((c & 3) << 4) + l15;  // D col = lane&15
      float4v a = acc[p][c];
      half4v hv = {(_Float16)a.x, (_Float16)a.y, (_Float16)a.z, (_Float16)a.w};
      *(half4v*)(preT + n * PRE_STRIDE + (quad << 2)) = hv;  // rows quad*4+reg
    }
    __syncthreads();

    const int rg = blockRow + (p << 4) + er;
    // LN1 stats per 256-chunk
    float mean1[4], rstd1[4];
#pragma unroll
    for (int ch = 0; ch < 4; ++ch) {
      float s = 0.f, q = 0.f;
#pragma unroll
      for (int ss = 0; ss < 8; ++ss) {
        int n = (ch << 8) + (ss << 5) + et;
        float v = (float)preT[n * PRE_STRIDE + er] + bias[n];
        s += v;
        q += v * v;
      }
#pragma unroll
      for (int m = 1; m < 32; m <<= 1) {
        s += __shfl_xor(s, m, 32);
        q += __shfl_xor(q, m, 32);
      }
      float mu = s * (1.0f / 256.0f);
      mean1[ch] = mu;
      rstd1[ch] = __frsqrt_rn(q * (1.0f / 256.0f) - mu * mu + 1e-5f);
    }

    float ncp[8], so[8], cv[8];
    float s2 = 0.f, q2 = 0.f;
#pragma unroll
    for (int ss = 0; ss < 8; ++ss) {
      int hc = (ss << 5) + et;
      float iv = ((float)preT[(hc)*PRE_STRIDE + er] + bias[hc] - mean1[0]) * rstd1[0] * g1[hc] + b1[hc];
      float jv = ((float)preT[(256 + hc) * PRE_STRIDE + er] + bias[256 + hc] - mean1[1]) * rstd1[1] * g1[256 + hc] + b1[256 + hc];
      float fv = ((float)preT[(512 + hc) * PRE_STRIDE + er] + bias[512 + hc] - mean1[2]) * rstd1[2] * g1[512 + hc] + b1[512 + hc];
      float ov = ((float)preT[(768 + hc) * PRE_STRIDE + er] + bias[768 + hc] - mean1[3]) * rstd1[3] * g1[768 + hc] + b1[768 + hc];
      float cval = cin[(size_t)rg * 256 + hc];
      float nc = cval * sigm(fv + 1.0f) + sigm(iv) * tanh_fast(jv);
      ncp[ss] = nc;
      so[ss] = sigm(ov);
      cv[ss] = cval;
      s2 += nc;
      q2 += nc * nc;
    }
#pragma unroll
    for (int m = 1; m < 32; m <<= 1) {
      s2 += __shfl_xor(s2, m, 32);
      q2 += __shfl_xor(q2, m, 32);
    }
    float mu2 = s2 * (1.0f / 256.0f);
    float rstd2 = __frsqrt_rn(q2 * (1.0f / 256.0f) - mu2 * mu2 + 1e-5f);
#pragma unroll
    for (int ss = 0; ss < 8; ++ss) {
      int hc = (ss << 5) + et;
      size_t gi = (size_t)rg * 256 + hc;
      float ncn = (ncp[ss] - mu2) * rstd2 * g2[hc] + b2[hc];
      float nh = tanh_fast(ncn) * so[ss];
      float hval = hin[gi];
      out_h[gi] = (mhp[gi] < 0.7f) ? nh : hval;   // zoneout: mask<keep -> new
      out_c[gi] = (mcp[gi] < 0.7f) ? ncn : cv[ss];
    }
  }
}

extern "C" void kernel_launch(void* const* d_in, const int* in_sizes, int n_in,
                              void* d_out, int out_size, void* d_ws, size_t ws_size,
                              hipStream_t stream) {
  (void)in_sizes; (void)n_in; (void)out_size; (void)ws_size;
  const float* x = (const float*)d_in[0];
  const float* h = (const float*)d_in[1];
  const float* c = (const float*)d_in[2];
  const float* W = (const float*)d_in[3];
  const float* bias = (const float*)d_in[4];
  const float* g1 = (const float*)d_in[5];
  const float* b1 = (const float*)d_in[6];
  const float* g2 = (const float*)d_in[7];
  const float* b2 = (const float*)d_in[8];
  const float* mh = (const float*)d_in[9];
  const float* mc = (const float*)d_in[10];
  _Float16* Wt = (_Float16*)d_ws;  // 1 MB

  wt_kernel<<<dim3(16, 8), dim3(256), 0, stream>>>(W, Wt);
  lstm_fused<<<dim3(1024), dim3(NTHREADS), 40960, stream>>>(
      x, h, c, Wt, bias, g1, b1, g2, b2, mh, mc, (float*)d_out);
}

// Round 2
// 508.787 us; speedup vs baseline: 2.8153x; 2.8153x over previous
//
#include <hip/hip_runtime.h>

// Fused LayerNorm-LSTM cell + zoneout for MI355X (gfx950).
// GEMM: concat(x,h)[65536x512] @ W[512x1024] via mfma_f32_16x16x32_f16,
// fused with block-LN(4x256), gates, LN(new_c), zoneout.
// Kernel 0 pre-transposes W to Wt[1024][512] fp16 in d_ws (needs 1 MB ws).
//
// R1 fix: epilogue pass loop is now FULLY UNROLLED. Round 1's `#pragma unroll 1`
// made acc[p][c] dynamically indexed -> compiler demoted acc[4][8] to scratch
// (VGPR_Count=92, WRITE_SIZE=4.69GB of spill traffic, MfmaUtil=2.2%).

#define NTHREADS 512
#define TILE_M 64
#define PRE_STRIDE 20  // halfs per n-row in epilogue scratch (16 rows + 4 pad)

typedef _Float16 half8 __attribute__((ext_vector_type(8)));
typedef _Float16 half4v __attribute__((ext_vector_type(4)));
typedef float float4v __attribute__((ext_vector_type(4)));

__device__ __forceinline__ void async16(const void* g, void* l) {
  __builtin_amdgcn_global_load_lds(
      (const __attribute__((address_space(1))) unsigned int*)g,
      (__attribute__((address_space(3))) unsigned int*)l, 16, 0, 0);
}

__device__ __forceinline__ float sigm(float x) {
  return __fdividef(1.0f, 1.0f + __expf(-x));
}
__device__ __forceinline__ float tanh_fast(float x) {
  return 2.0f * __fdividef(1.0f, 1.0f + __expf(-2.0f * x)) - 1.0f;
}

// ---- Kernel 0: W[512][1024] fp32 -> Wt[1024][512] fp16 (tiled transpose) ----
__global__ __launch_bounds__(256) void wt_kernel(const float* __restrict__ W,
                                                 _Float16* __restrict__ Wt) {
  __shared__ float tile[64][65];
  const int bn = blockIdx.x << 6;  // n block (16)
  const int bk = blockIdx.y << 6;  // k block (8)
  const int tid = threadIdx.x;
#pragma unroll
  for (int i = 0; i < 16; ++i) {
    int idx = (i << 8) + tid;
    int kk = idx >> 6, nn = idx & 63;
    tile[kk][nn] = W[(size_t)(bk + kk) * 1024 + bn + nn];
  }
  __syncthreads();
#pragma unroll
  for (int i = 0; i < 16; ++i) {
    int idx = (i << 8) + tid;
    int nn = idx >> 6, kk = idx & 63;
    Wt[(size_t)(bn + nn) * 512 + bk + kk] = (_Float16)tile[kk][nn];
  }
}

// ---- Main fused kernel ----
// Block: 64 rows x all 1024 cols. K-loop BK=32, W staged in two 512-col halves.
// LDS phase A: aT 64x32 halfs (4KB, 16B-chunk XOR swizzle) + wTh 512x32 halfs (32KB).
// LDS phase B: preT[1024][PRE_STRIDE] halfs (40KB), col-major (n-major, row inner).
__global__ __launch_bounds__(NTHREADS, 2) void lstm_fused(
    const float* __restrict__ x, const float* __restrict__ hin,
    const float* __restrict__ cin, const _Float16* __restrict__ Wt,
    const float* __restrict__ bias, const float* __restrict__ g1,
    const float* __restrict__ b1, const float* __restrict__ g2,
    const float* __restrict__ b2, const float* __restrict__ mhp,
    const float* __restrict__ mcp, float* __restrict__ out) {
  extern __shared__ char smem[];
  _Float16* aT = (_Float16*)smem;            // 4KB
  _Float16* wTh = (_Float16*)(smem + 4096);  // 32KB
  _Float16* preT = (_Float16*)smem;          // 40KB (phase B, reuses phase A)

  const int tid = threadIdx.x;
  const int wave = tid >> 6;
  const int lane = tid & 63;
  const int l15 = lane & 15;
  const int quad = lane >> 4;
  const int blockRow = blockIdx.x * TILE_M;

  float4v acc[4][8];
#pragma unroll
  for (int s = 0; s < 4; ++s)
#pragma unroll
    for (int c = 0; c < 8; ++c) acc[s][c] = (float4v){0.f, 0.f, 0.f, 0.f};

  // A staging: thread -> (row=tid>>3, 4 k's at (tid&7)*4), fp32->fp16, swizzled chunk
  const int arow = tid >> 3;
  const int ap4 = (tid & 7) << 2;
  const float* xrow = x + (size_t)(blockRow + arow) * 256 + ap4;
  const float* hrow = hin + (size_t)(blockRow + arow) * 256 + ap4;
  _Float16* adst = aT + arow * 32 + (((ap4 >> 3) ^ (arow & 3)) << 3) + (ap4 & 4);

  // W staging: lane-linear LDS (global_load_lds constraint); global chunk XOR-permuted
  const int wnl0 = tid >> 2;                  // local n row 0..127 (+ it*128)
  const int wj = (tid & 3) ^ (wnl0 & 3);      // global 16B chunk to fetch
  const char* wg = (const char*)Wt + (size_t)wnl0 * 1024 + wj * 16;
  char* wl = (char*)wTh + tid * 16;

  const int aslot = quad ^ (l15 & 3);  // swizzled chunk slot for all frag reads

  for (int iter = 0; iter < 16; ++iter) {
    {  // stage A tile (k window iter*32..+31 of concat(x,h))
      const float* src = (iter < 8) ? (xrow + iter * 32) : (hrow + (iter - 8) * 32);
      float4 v = *(const float4*)src;
      half4v hv = {(_Float16)v.x, (_Float16)v.y, (_Float16)v.z, (_Float16)v.w};
      *(half4v*)adst = hv;
    }
#pragma unroll
    for (int it = 0; it < 4; ++it)  // stage W cols 0..511
      async16(wg + it * 131072 + iter * 64, wl + it * 8192);
    __syncthreads();

    half8 af[4];
#pragma unroll
    for (int s = 0; s < 4; ++s)
      af[s] = *(const half8*)(aT + (s * 16 + l15) * 32 + aslot * 8);
    {
      half8 bf[4];
#pragma unroll
      for (int cc = 0; cc < 4; ++cc) {
        int nl = wave * 64 + cc * 16 + l15;
        bf[cc] = *(const half8*)(wTh + nl * 32 + aslot * 8);
      }
#pragma unroll
      for (int s = 0; s < 4; ++s)
#pragma unroll
        for (int cc = 0; cc < 4; ++cc)
          acc[s][cc] = __builtin_amdgcn_mfma_f32_16x16x32_f16(af[s], bf[cc], acc[s][cc], 0, 0, 0);
    }
    __syncthreads();
#pragma unroll
    for (int it = 0; it < 4; ++it)  // stage W cols 512..1023
      async16(wg + 524288 + it * 131072 + iter * 64, wl + it * 8192);
    __syncthreads();
    {
      half8 bf[4];
#pragma unroll
      for (int cc = 0; cc < 4; ++cc) {
        int nl = wave * 64 + cc * 16 + l15;
        bf[cc] = *(const half8*)(wTh + nl * 32 + aslot * 8);
      }
#pragma unroll
      for (int s = 0; s < 4; ++s)
#pragma unroll
        for (int cc = 0; cc < 4; ++cc)
          acc[s][4 + cc] =
              __builtin_amdgcn_mfma_f32_16x16x32_f16(af[s], bf[cc], acc[s][4 + cc], 0, 0, 0);
    }
    __syncthreads();
  }

  // ---- Epilogue: 4 passes of 16 rows (pass p == row-stripe p) ----
  // FULLY UNROLLED so acc[p][*] indices are compile-time constants (keeps acc
  // in registers; dynamic p in R1 demoted acc to scratch -> 4.3GB spill traffic).
  float* out_h = out;
  float* out_c = out + (size_t)65536 * 256;
  const int er = tid >> 5;  // row in pass 0..15
  const int et = tid & 31;  // col phase: cols {et, et+32, ..., et+224}

#pragma unroll
  for (int p = 0; p < 4; ++p) {
    __syncthreads();
    // write acc stripe p -> preT (col-major: [n][row]), b64 per 4 rows
#pragma unroll
    for (int c = 0; c < 8; ++c) {
      int n = ((c >> 2) << 9) + wave * 64 + ((c & 3) << 4) + l15;  // D col = lane&15
      float4v a = acc[p][c];
      half4v hv = {(_Float16)a.x, (_Float16)a.y, (_Float16)a.z, (_Float16)a.w};
      *(half4v*)(preT + n * PRE_STRIDE + (quad << 2)) = hv;  // rows quad*4+reg
    }
    __syncthreads();

    const int rg = blockRow + (p << 4) + er;
    // LN1 stats per 256-chunk
    float mean1[4], rstd1[4];
#pragma unroll
    for (int ch = 0; ch < 4; ++ch) {
      float s = 0.f, q = 0.f;
#pragma unroll
      for (int ss = 0; ss < 8; ++ss) {
        int n = (ch << 8) + (ss << 5) + et;
        float v = (float)preT[n * PRE_STRIDE + er] + bias[n];
        s += v;
        q += v * v;
      }
#pragma unroll
      for (int m = 1; m < 32; m <<= 1) {
        s += __shfl_xor(s, m, 32);
        q += __shfl_xor(q, m, 32);
      }
      float mu = s * (1.0f / 256.0f);
      mean1[ch] = mu;
      rstd1[ch] = __frsqrt_rn(q * (1.0f / 256.0f) - mu * mu + 1e-5f);
    }

    float ncp[8], so[8], cv[8];
    float s2 = 0.f, q2 = 0.f;
#pragma unroll
    for (int ss = 0; ss < 8; ++ss) {
      int hc = (ss << 5) + et;
      float iv = ((float)preT[(hc)*PRE_STRIDE + er] + bias[hc] - mean1[0]) * rstd1[0] * g1[hc] + b1[hc];
      float jv = ((float)preT[(256 + hc) * PRE_STRIDE + er] + bias[256 + hc] - mean1[1]) * rstd1[1] * g1[256 + hc] + b1[256 + hc];
      float fv = ((float)preT[(512 + hc) * PRE_STRIDE + er] + bias[512 + hc] - mean1[2]) * rstd1[2] * g1[512 + hc] + b1[512 + hc];
      float ov = ((float)preT[(768 + hc) * PRE_STRIDE + er] + bias[768 + hc] - mean1[3]) * rstd1[3] * g1[768 + hc] + b1[768 + hc];
      float cval = cin[(size_t)rg * 256 + hc];
      float nc = cval * sigm(fv + 1.0f) + sigm(iv) * tanh_fast(jv);
      ncp[ss] = nc;
      so[ss] = sigm(ov);
      cv[ss] = cval;
      s2 += nc;
      q2 += nc * nc;
    }
#pragma unroll
    for (int m = 1; m < 32; m <<= 1) {
      s2 += __shfl_xor(s2, m, 32);
      q2 += __shfl_xor(q2, m, 32);
    }
    float mu2 = s2 * (1.0f / 256.0f);
    float rstd2 = __frsqrt_rn(q2 * (1.0f / 256.0f) - mu2 * mu2 + 1e-5f);
#pragma unroll
    for (int ss = 0; ss < 8; ++ss) {
      int hc = (ss << 5) + et;
      size_t gi = (size_t)rg * 256 + hc;
      float ncn = (ncp[ss] - mu2) * rstd2 * g2[hc] + b2[hc];
      float nh = tanh_fast(ncn) * so[ss];
      float hval = hin[gi];
      out_h[gi] = (mhp[gi] < 0.7f) ? nh : hval;   // zoneout: mask<keep -> new
      out_c[gi] = (mcp[gi] < 0.7f) ? ncn : cv[ss];
    }
  }
}

extern "C" void kernel_launch(void* const* d_in, const int* in_sizes, int n_in,
                              void* d_out, int out_size, void* d_ws, size_t ws_size,
                              hipStream_t stream) {
  (void)in_sizes; (void)n_in; (void)out_size; (void)ws_size;
  const float* x = (const float*)d_in[0];
  const float* h = (const float*)d_in[1];
  const float* c = (const float*)d_in[2];
  const float* W = (const float*)d_in[3];
  const float* bias = (const float*)d_in[4];
  const float* g1 = (const float*)d_in[5];
  const float* b1 = (const float*)d_in[6];
  const float* g2 = (const float*)d_in[7];
  const float* b2 = (const float*)d_in[8];
  const float* mh = (const float*)d_in[9];
  const float* mc = (const float*)d_in[10];
  _Float16* Wt = (_Float16*)d_ws;  // 1 MB

  wt_kernel<<<dim3(16, 8), dim3(256), 0, stream>>>(W, Wt);
  lstm_fused<<<dim3(1024), dim3(NTHREADS), 40960, stream>>>(
      x, h, c, Wt, bias, g1, b1, g2, b2, mh, mc, (float*)d_out);
}